// Round 1
// baseline (2412.422 us; speedup 1.0000x reference)
//
#include <hip/hip_runtime.h>

// SparseGO: out[b][t] = sum_g x[b][g] * (weight[g][t] * mask[g][t])
// mask has <= 4 nonzeros (value 1.0) per gene row g.
// Strategy: (1) compact mask+weight into a per-gene table of <=4 (term, w)
// pairs (padded with w=0); (2) scatter-SpMM with per-block LDS accumulators
// over R batch rows.

#define BATCH  4096
#define GENES  20000
#define NTERMS 5000
#define MAXNZ  4
#define RROWS  2   // batch rows per block; 2*5000*4B = 40 KB LDS -> 4 blocks/CU

__global__ __launch_bounds__(256) void build_table(
    const float* __restrict__ mask, const float* __restrict__ weight,
    int* __restrict__ terms, float* __restrict__ wvals) {
  const int g = blockIdx.x;
  __shared__ int cnt;
  if (threadIdx.x == 0) cnt = 0;
  __syncthreads();

  const float4* row = (const float4*)(mask + (size_t)g * NTERMS);
  const int n4 = NTERMS / 4;  // 1250, exact
  for (int i = threadIdx.x; i < n4; i += 256) {
    float4 m = row[i];
    if (m.x != 0.f || m.y != 0.f || m.z != 0.f || m.w != 0.f) {
      const float mv[4] = {m.x, m.y, m.z, m.w};
#pragma unroll
      for (int j = 0; j < 4; ++j) {
        if (mv[j] != 0.f) {
          int slot = atomicAdd(&cnt, 1);
          if (slot < MAXNZ) {
            int t = i * 4 + j;
            terms[g * MAXNZ + slot] = t;
            wvals[g * MAXNZ + slot] = weight[(size_t)g * NTERMS + t];
          }
        }
      }
    }
  }
  __syncthreads();
  if (threadIdx.x == 0) {
    int c = cnt < MAXNZ ? cnt : MAXNZ;
    for (int s = c; s < MAXNZ; ++s) {
      terms[g * MAXNZ + s] = 0;
      wvals[g * MAXNZ + s] = 0.f;
    }
  }
}

__global__ __launch_bounds__(256) void spmm_scatter(
    const float* __restrict__ x,
    const int* __restrict__ terms, const float* __restrict__ wvals,
    float* __restrict__ out) {
  __shared__ float acc[RROWS * NTERMS];  // 40 KB
  for (int i = threadIdx.x; i < RROWS * NTERMS; i += 256) acc[i] = 0.f;
  __syncthreads();

  const int b0 = blockIdx.x * RROWS;
  for (int g = threadIdx.x; g < GENES; g += 256) {
    const int4  t4 = ((const int4*)terms)[g];
    const float4 w4 = ((const float4*)wvals)[g];
#pragma unroll
    for (int r = 0; r < RROWS; ++r) {
      const float xv = x[(size_t)(b0 + r) * GENES + g];
      float* a = acc + r * NTERMS;
      atomicAdd(&a[t4.x], xv * w4.x);
      atomicAdd(&a[t4.y], xv * w4.y);
      atomicAdd(&a[t4.z], xv * w4.z);
      atomicAdd(&a[t4.w], xv * w4.w);
    }
  }
  __syncthreads();

#pragma unroll
  for (int r = 0; r < RROWS; ++r) {
    const float* a = acc + r * NTERMS;
    float* o = out + (size_t)(b0 + r) * NTERMS;
    for (int t = threadIdx.x; t < NTERMS; t += 256) o[t] = a[t];
  }
}

extern "C" void kernel_launch(void* const* d_in, const int* in_sizes, int n_in,
                              void* d_out, int out_size, void* d_ws, size_t ws_size,
                              hipStream_t stream) {
  const float* x      = (const float*)d_in[0];
  const float* weight = (const float*)d_in[1];
  const float* mask   = (const float*)d_in[2];
  float* out = (float*)d_out;

  int*   terms = (int*)d_ws;                                        // 320 KB
  float* wvals = (float*)((char*)d_ws + (size_t)GENES * MAXNZ * 4); // 320 KB

  build_table<<<GENES, 256, 0, stream>>>(mask, weight, terms, wvals);
  spmm_scatter<<<BATCH / RROWS, 256, 0, stream>>>(x, terms, wvals, out);
}